// Round 5
// baseline (75.442 us; speedup 1.0000x reference)
//
#include <hip/hip_runtime.h>

typedef __bf16 bf16_t;
typedef bf16_t bf16x8 __attribute__((ext_vector_type(8)));
typedef float f32x4 __attribute__((ext_vector_type(4)));

#define Bsz 4096   // batch rows (M)
#define Csz 4096   // centers (N)
#define Dsz 1024   // data dim (K)
#define BM 128
#define BN 128
#define BK 64
#define NKT (Dsz/BK)        // 16 K-tiles
#define NPC 64              // partial column-groups: 32 bn-tiles x 2 wc

// RNE f32 -> bf16 bits
__device__ inline unsigned short f2bf(float f){
  unsigned u = __float_as_uint(f);
  u += 0x7FFFu + ((u >> 16) & 1u);
  return (unsigned short)(u >> 16);
}

// inline-asm LDS read: opaque to alias analysis, so the compiler cannot
// insert vmcnt(0) drains against the global_load_lds prefetch queue.
__device__ __forceinline__ bf16x8 dsr128(unsigned byte_off){
  bf16x8 r;
  asm volatile("ds_read_b128 %0, %1" : "=v"(r) : "v"(byte_off));
  return r;
}

// ---------------- prep: x2/c2 (f32 exact) + bf16 conversion ----------------
__global__ __launch_bounds__(256) void prep_kernel(
    const float* __restrict__ x, const float* __restrict__ cen,
    unsigned short* __restrict__ xb, unsigned short* __restrict__ cb,
    float* __restrict__ x2, float* __restrict__ c2)
{
  int w = blockIdx.x * 4 + (threadIdx.x >> 6);   // global wave id, one row each
  int lane = threadIdx.x & 63;
  const float* src; unsigned short* dst; float* sq; int row;
  if (w < Bsz) { row = w;       src = x;   dst = xb; sq = x2; }
  else         { row = w - Bsz; src = cen; dst = cb; sq = c2; }

  const float4* s4 = (const float4*)(src + (size_t)row * Dsz);
  unsigned short* d = dst + (size_t)row * Dsz;
  float ss = 0.f;
  #pragma unroll
  for (int t = 0; t < 4; ++t){
    float4 v = s4[t * 64 + lane];
    ss += v.x*v.x + v.y*v.y + v.z*v.z + v.w*v.w;
    ushort4 u; u.x = f2bf(v.x); u.y = f2bf(v.y); u.z = f2bf(v.z); u.w = f2bf(v.w);
    *(ushort4*)(d + (size_t)(t * 64 + lane) * 4) = u;
  }
  #pragma unroll
  for (int off = 32; off >= 1; off >>= 1) ss += __shfl_xor(ss, off, 64);
  if (lane == 0) sq[row] = ss;
}

// ------------- 128x128 2-block/CU fused GEMM + RBF epilogue -------------
// 256 thr = 4 waves (2 wr x 2 wc). Per wave: 64x64 output = 4x4 frags 16x16.
// LDS: 2 bufs x (A 128x64 + B 128x64) bf16 = 64 KiB -> 2 blocks/CU resident.
// XOR chunk swizzle: LDS[r][c16] = G[r][c16 ^ (r&7)] (linear gload_lds dest,
// pre-swizzled source, swizzled read offsets). Per K-tile ONE barrier:
//   kk0 reads -> stage next tile (8 gload_lds) -> lgkm0 -> 16 MFMA
//   -> kk1 reads -> lgkm0 -> 16 MFMA -> vmcnt(0) -> barrier.
// Inter-block overlap (2 blocks/CU) hides the stage latency the barrier exposes.
__global__ __launch_bounds__(256, 2) void rbf_gemm_kernel(
    const unsigned short* __restrict__ xb, const unsigned short* __restrict__ cb,
    const float* __restrict__ x2, const float* __restrict__ c2,
    const float* __restrict__ beta, const float* __restrict__ W,
    float* __restrict__ partials)
{
  __shared__ __align__(16) unsigned short smem[32768];  // 64 KiB

  const int tid  = threadIdx.x;
  const int wid  = tid >> 6;
  const int lane = tid & 63;
  const int wr   = wid >> 1;        // 0..1
  const int wc   = wid & 1;         // 0..1
  const int l15  = lane & 15;
  const int lhi  = lane >> 4;

  // XCD mapping: xcd = id%8; each XCD owns two 8x8 (bm,bn) rects -> 4 MB
  // working set per XCD (= its L2).
  const int id   = blockIdx.x;          // 0..1023
  const int xcd  = id & 7;
  const int jj   = id >> 3;             // 0..127
  const int rect = xcd + 8 * (jj >> 6); // 0..15
  const int pos  = jj & 63;             // 0..63
  const int bm   = (rect & 3) * 8 + (pos & 7);
  const int bn   = (rect >> 2) * 8 + (pos >> 3);

  const unsigned short* gA = xb + (size_t)(bm * BM) * Dsz;
  const unsigned short* gB = cb + (size_t)(bn * BN) * Dsz;

  // staging: one gload_lds = 64 lanes x 16B = 8 rows; 256 thr cover 32 rows;
  // 4 passes cover a 128-row panel.
  const int srow   = tid >> 3;                 // 0..31
  const int schunk = (tid & 7) ^ (srow & 7);   // pre-swizzled source 16B chunk

  // read-side swizzled byte offsets (chunk = (kk*4+lhi) ^ (l15&7))
  const unsigned lds_base =
      (unsigned)(uintptr_t)(__attribute__((address_space(3))) unsigned short*)smem;
  const unsigned aoff0 = lds_base + (unsigned)((wr*64 + l15)*128 + ((lhi)    ^ (l15 & 7))*16);
  const unsigned aoff1 = lds_base + (unsigned)((wr*64 + l15)*128 + ((4+lhi) ^ (l15 & 7))*16);
  const unsigned boff0 = lds_base + 16384u + (unsigned)((wc*64 + l15)*128 + ((lhi)    ^ (l15 & 7))*16);
  const unsigned boff1 = lds_base + 16384u + (unsigned)((wc*64 + l15)*128 + ((4+lhi) ^ (l15 & 7))*16);

#define STAGE_P(GP, LBASE, KT) { \
    _Pragma("unroll") \
    for (int r_ = 0; r_ < 4; ++r_){ \
      const unsigned short* gsrc_ = (GP) + (size_t)(r_*32 + srow) * Dsz + (KT)*BK + schunk*8; \
      __builtin_amdgcn_global_load_lds( \
        (const __attribute__((address_space(1))) unsigned int*)gsrc_, \
        (__attribute__((address_space(3))) unsigned int*)&smem[(LBASE) + r_*2048 + wid*512], 16, 0, 0); \
    } }

  // stage the FULL tile KT into buf P (8 gload_lds per thread)
#define STAGE_T(P, KT) { \
    STAGE_P(gA, (P)*16384,        KT) \
    STAGE_P(gB, (P)*16384 + 8192, KT) }

  f32x4 acc[4][4];
  #pragma unroll
  for (int mi = 0; mi < 4; ++mi)
    #pragma unroll
    for (int ni = 0; ni < 4; ++ni)
      acc[mi][ni] = (f32x4){0.f, 0.f, 0.f, 0.f};

  bf16x8 av[4], bv[4];

#define LD_A(P, KK) { \
    _Pragma("unroll") \
    for (int mi_ = 0; mi_ < 4; ++mi_) \
      av[mi_] = dsr128((KK ? aoff1 : aoff0) + (P)*32768u + mi_*2048u); }

#define LD_B(P, KK) { \
    _Pragma("unroll") \
    for (int ni_ = 0; ni_ < 4; ++ni_) \
      bv[ni_] = dsr128((KK ? boff1 : boff0) + (P)*32768u + ni_*2048u); }

#define MFMA16 { \
    _Pragma("unroll") \
    for (int mi_ = 0; mi_ < 4; ++mi_) \
      _Pragma("unroll") \
      for (int ni_ = 0; ni_ < 4; ++ni_) \
        acc[mi_][ni_] = __builtin_amdgcn_mfma_f32_16x16x32_bf16(av[mi_], bv[ni_], acc[mi_][ni_], 0,0,0); }

  // Prologue: stage tile 0 into buf0, drain, sync.
  STAGE_T(0, 0)
  asm volatile("s_waitcnt vmcnt(0)" ::: "memory");
  __builtin_amdgcn_s_barrier();

  #pragma unroll 2
  for (int t = 0; t < NKT; ++t){
    const int p = t & 1;
    LD_B(p, 0)
    LD_A(p, 0)
    if (t + 1 < NKT) STAGE_T(1 - p, t + 1)
    asm volatile("s_waitcnt lgkmcnt(0)" ::: "memory");
    __builtin_amdgcn_sched_barrier(0);
    __builtin_amdgcn_s_setprio(1);
    MFMA16
    __builtin_amdgcn_s_setprio(0);
    __builtin_amdgcn_sched_barrier(0);
    LD_A(p, 1)
    LD_B(p, 1)
    asm volatile("s_waitcnt lgkmcnt(0)" ::: "memory");
    __builtin_amdgcn_sched_barrier(0);
    __builtin_amdgcn_s_setprio(1);
    MFMA16
    __builtin_amdgcn_s_setprio(0);
    __builtin_amdgcn_sched_barrier(0);
    asm volatile("s_waitcnt vmcnt(0)" ::: "memory");   // stages ~1 tile old
    __builtin_amdgcn_sched_barrier(0);
    __builtin_amdgcn_s_barrier();                      // the ONLY barrier/tile
  }

  // ---- fused epilogue: d2 -> dist -> exp -> *W, then column-sum ----
  const int rowbase0 = bm * BM + wr * 64;
  f32x4 rs[4];
  #pragma unroll
  for (int mi = 0; mi < 4; ++mi) rs[mi] = (f32x4){0.f, 0.f, 0.f, 0.f};

  f32x4 x2r[4];
  #pragma unroll
  for (int mi = 0; mi < 4; ++mi)
    x2r[mi] = *(const f32x4*)&x2[rowbase0 + mi * 16 + lhi * 4];

  #pragma unroll
  for (int ni = 0; ni < 4; ++ni){
    const int col = bn * BN + wc * 64 + ni * 16 + l15;
    const float c2v = c2[col], bt = beta[col], wv = W[col];
    #pragma unroll
    for (int mi = 0; mi < 4; ++mi)
      #pragma unroll
      for (int j = 0; j < 4; ++j){
        float s    = acc[mi][ni][j];
        float d2   = x2r[mi][j] + c2v - 2.0f * s;
        float dist = sqrtf(fmaxf(d2, 0.0f));
        rs[mi][j] += wv * __expf(-bt * dist);   // exp(<=0) can't be inf
      }
  }

  // reduce over the 16 lanes holding different cols; write per-(bn,wc) partials
  const size_t pcbase = (size_t)(bn * 2 + wc) * Bsz;
  #pragma unroll
  for (int mi = 0; mi < 4; ++mi){
    #pragma unroll
    for (int j = 0; j < 4; ++j){
      float v = rs[mi][j];
      v += __shfl_xor(v, 1, 16);
      v += __shfl_xor(v, 2, 16);
      v += __shfl_xor(v, 4, 16);
      v += __shfl_xor(v, 8, 16);
      rs[mi][j] = v;
    }
    if (l15 == 0)
      *(f32x4*)&partials[pcbase + rowbase0 + mi * 16 + lhi * 4] = rs[mi];
  }
}

// ---------------- final reduction over column-groups ----------------
__global__ __launch_bounds__(256) void reduce_kernel(
    const float* __restrict__ partials, const float* __restrict__ bias,
    float* __restrict__ out)
{
  int b = blockIdx.x * 256 + threadIdx.x;
  float s = bias[0];
  #pragma unroll
  for (int t = 0; t < NPC; ++t) s += partials[(size_t)t * Bsz + b];
  out[b] = s;
}

// ---------------- naive f32 fallback (only if ws too small) ----------------
__global__ __launch_bounds__(256) void rbf_naive_kernel(
    const float* __restrict__ x, const float* __restrict__ cen,
    const float* __restrict__ beta, const float* __restrict__ W,
    const float* __restrict__ bias, float* __restrict__ out)
{
  __shared__ float4 xs4[Dsz / 4];
  __shared__ float red[256];
  int b = blockIdx.x;
  for (int i = threadIdx.x; i < Dsz / 4; i += 256)
    xs4[i] = ((const float4*)(x + (size_t)b * Dsz))[i];
  __syncthreads();
  float acc = 0.f;
  for (int j = threadIdx.x; j < Csz; j += 256){
    const float4* c4 = (const float4*)(cen + (size_t)j * Dsz);
    float d2 = 0.f;
    for (int k = 0; k < Dsz / 4; ++k){
      float4 cv = c4[k], xv = xs4[k];
      float a0 = xv.x - cv.x, a1 = xv.y - cv.y, a2 = xv.z - cv.z, a3 = xv.w - cv.w;
      d2 += a0*a0 + a1*a1 + a2*a2 + a3*a3;
    }
    acc += W[j] * expf(-beta[j] * sqrtf(fmaxf(d2, 0.f)));
  }
  red[threadIdx.x] = acc;
  __syncthreads();
  for (int s = 128; s >= 1; s >>= 1){
    if (threadIdx.x < s) red[threadIdx.x] += red[threadIdx.x + s];
    __syncthreads();
  }
  if (threadIdx.x == 0) out[b] = red[0] + bias[0];
}

extern "C" void kernel_launch(void* const* d_in, const int* in_sizes, int n_in,
                              void* d_out, int out_size, void* d_ws, size_t ws_size,
                              hipStream_t stream)
{
  const float* x    = (const float*)d_in[0];
  const float* cen  = (const float*)d_in[1];
  const float* beta = (const float*)d_in[2];
  const float* W    = (const float*)d_in[3];
  const float* bias = (const float*)d_in[4];
  float* out = (float*)d_out;

  const size_t off_xb = 0;
  const size_t off_cb = off_xb + (size_t)Bsz * Dsz * sizeof(unsigned short);
  const size_t off_x2 = off_cb + (size_t)Csz * Dsz * sizeof(unsigned short);
  const size_t off_c2 = off_x2 + (size_t)Bsz * sizeof(float);
  const size_t off_p  = off_c2 + (size_t)Csz * sizeof(float);
  const size_t need   = off_p  + (size_t)NPC * Bsz * sizeof(float);

  if (ws_size < need){
    rbf_naive_kernel<<<Bsz, 256, 0, stream>>>(x, cen, beta, W, bias, out);
    return;
  }

  char* ws = (char*)d_ws;
  unsigned short* xb = (unsigned short*)(ws + off_xb);
  unsigned short* cb = (unsigned short*)(ws + off_cb);
  float* x2 = (float*)(ws + off_x2);
  float* c2 = (float*)(ws + off_c2);
  float* pp = (float*)(ws + off_p);

  prep_kernel<<<(Bsz + Csz) / 4, 256, 0, stream>>>(x, cen, xb, cb, x2, c2);
  rbf_gemm_kernel<<<1024, 256, 0, stream>>>(xb, cb, x2, c2, beta, W, pp);
  reduce_kernel<<<Bsz / 256, 256, 0, stream>>>(pp, bias, out);
}